// Round 10
// baseline (342.722 us; speedup 1.0000x reference)
//
#include <hip/hip_runtime.h>

#define U_NODES 200000
#define B_ROWS  20000
#define K_S     33
#define F_DIM   256
#define E_DIM   128
#define NBLK    1563            // ceil(U_NODES / 128)

typedef __bf16 bf16x8 __attribute__((ext_vector_type(8)));
typedef float  f32x4  __attribute__((ext_vector_type(4)));
typedef unsigned short ushortx4 __attribute__((ext_vector_type(4)));
typedef unsigned short ushortx8 __attribute__((ext_vector_type(8)));

typedef const __attribute__((address_space(1))) void* gptr_t;
typedef __attribute__((address_space(3))) void* lptr_t;

__device__ __forceinline__ unsigned short f2bf(float f) {
    unsigned int u = __builtin_bit_cast(unsigned int, f);
    u += 0x7fffu + ((u >> 16) & 1u);            // round-to-nearest-even
    return (unsigned short)(u >> 16);
}
__device__ __forceinline__ float bf2f(unsigned short s) {
    return __builtin_bit_cast(float, ((unsigned int)s) << 16);
}
__device__ __forceinline__ bf16x8 pack_bf8(f32x4 a, f32x4 b) {
    ushortx8 r;
    r[0] = f2bf(a[0]); r[1] = f2bf(a[1]); r[2] = f2bf(a[2]); r[3] = f2bf(a[3]);
    r[4] = f2bf(b[0]); r[5] = f2bf(b[1]); r[6] = f2bf(b[2]); r[7] = f2bf(b[3]);
    return __builtin_bit_cast(bf16x8, r);
}

// ---------------------------------------------------------------------------
// One-time prep: Wt[n][k] = bf16(W[k][n]) so B-fragments are contiguous-k.
// ---------------------------------------------------------------------------
__global__ void wprep_kernel(const float* __restrict__ W, unsigned short* __restrict__ Wt) {
    int n = blockIdx.x;      // 128
    int k = threadIdx.x;     // 256
    Wt[n * F_DIM + k] = f2bf(W[(size_t)k * E_DIM + n]);
}

// ---------------------------------------------------------------------------
// MFMA bf16 GEMM: h = bf16(A @ W), fused BN column sum/sumsq.
// v9: BK=32 occupancy/granularity experiment. v1-v8 span 117-125 us across
// maximally different schedules; all share <=3 blocks/CU residency. Halving
// the K-chunk cuts loop LDS to 24 KB (declared 32 KB for the epilogue
// transpose) -> 4 blocks/CU (VGPR-capped), 16 waves/CU, and finer
// stage/compute quanta for cross-block interleave (m114: cross-block overlap
// is the real latency hider in this structure).
// Staging: async global_load_lds (v8-verified), both-sides XOR swizzle
// (rule #21): A rows = 8x16B slots, sl^(r&7) (2-way read, free); W rows =
// 4x16B slots, sl^(rb&3) (4-way within 16-lane phase, 1.58x on small share).
// Epilogue/stats identical to R2/R9-verified code.
// ---------------------------------------------------------------------------
__global__ __launch_bounds__(256) void gemm_stats_kernel(
    const float* __restrict__ A, const unsigned short* __restrict__ Wt,
    unsigned short* __restrict__ h, float* __restrict__ partial)
{
    __shared__ __attribute__((aligned(16))) char smem[32768];
    char* As = smem;            // [128 r][8 slot][16B] fp32, swizzled, 16 KB
    char* Ws = smem + 16384;    // [128 n][4 slot][16B] bf16, swizzled,  8 KB

    const int t    = threadIdx.x;
    const int lane = t & 63;
    const int wv   = t >> 6;        // wave 0..3
    const int m    = lane & 15;
    const int qd   = lane >> 4;     // k-quad 0..3
    const int row0 = blockIdx.x * 128;
    const int wb   = t & 192;       // wave base (wv*64), wave-uniform

    const int r0 = wv * 32 + m;     // local rows this lane computes
    const int r1 = r0 + 16;

    f32x4 acc0[8], acc1[8];
    #pragma unroll
    for (int ct = 0; ct < 8; ++ct) {
        acc0[ct] = (f32x4){0.f, 0.f, 0.f, 0.f};
        acc1[ct] = (f32x4){0.f, 0.f, 0.f, 0.f};
    }

    for (int kk = 0; kk < F_DIM; kk += 32) {
        // ---- async stage A chunk [128][32] f32: 4 x global_load_lds(16B) ----
        // LDS[row][sl] = global[row][sl^(row&7)]; read at c^(row&7) -> col c.
        #pragma unroll
        for (int i = 0; i < 4; ++i) {
            int S   = i * 256 + t;
            int row = S >> 3, sl = S & 7;
            int gr  = row0 + row; if (gr >= U_NODES) gr = U_NODES - 1;
            const float* gsrc = A + (size_t)gr * F_DIM + kk + ((sl ^ (row & 7)) << 2);
            __builtin_amdgcn_global_load_lds(
                (gptr_t)gsrc, (lptr_t)(As + ((i * 256 + wb) << 4)), 16, 0, 0);
        }
        // ---- async stage W chunk [128][32] bf16: 2 x global_load_lds(16B) ----
        #pragma unroll
        for (int i = 0; i < 2; ++i) {
            int S   = i * 256 + t;
            int row = S >> 2, sl = S & 3;
            const unsigned short* gsrc = Wt + (size_t)row * F_DIM + kk + ((sl ^ (row & 3)) << 3);
            __builtin_amdgcn_global_load_lds(
                (gptr_t)gsrc, (lptr_t)(Ws + ((i * 256 + wb) << 4)), 16, 0, 0);
        }
        __syncthreads();    // vmcnt(0) drain -> chunk ready (other blocks hide)

        // ---- compute: 16 MFMA (one K=32 step) ----
        f32x4 a0lo = *(const f32x4*)(As + r0 * 128 + (((qd * 2)     ^ (r0 & 7)) << 4));
        f32x4 a0hi = *(const f32x4*)(As + r0 * 128 + (((qd * 2 + 1) ^ (r0 & 7)) << 4));
        f32x4 a1lo = *(const f32x4*)(As + r1 * 128 + (((qd * 2)     ^ (r1 & 7)) << 4));
        f32x4 a1hi = *(const f32x4*)(As + r1 * 128 + (((qd * 2 + 1) ^ (r1 & 7)) << 4));
        bf16x8 a0 = pack_bf8(a0lo, a0hi);
        bf16x8 a1 = pack_bf8(a1lo, a1hi);
        #pragma unroll
        for (int ct = 0; ct < 8; ++ct) {
            int rb = ct * 16 + m;
            bf16x8 b = *(const bf16x8*)(Ws + rb * 64 + (((qd) ^ (rb & 3)) << 4));
            acc0[ct] = __builtin_amdgcn_mfma_f32_16x16x32_bf16(a0, b, acc0[ct], 0, 0, 0);
            acc1[ct] = __builtin_amdgcn_mfma_f32_16x16x32_bf16(a1, b, acc1[ct], 0, 0, 0);
        }
        __syncthreads();    // all waves done reading before next-chunk DMA
    }

    // ---- fused BN stats (mask clamped tail rows) ----
    // D layout (m89-verified): col = lane&15, row = (lane>>4)*4 + reg
    const bool full = (row0 + 128) <= U_NODES;
    float s[8], sq[8];
    #pragma unroll
    for (int ct = 0; ct < 8; ++ct) {
        float ss = 0.f, qq = 0.f;
        #pragma unroll
        for (int v = 0; v < 4; ++v) {
            float x0 = acc0[ct][v];
            float x1 = acc1[ct][v];
            if (full || (row0 + wv * 32 + qd * 4 + v) < U_NODES)      { ss += x0; qq += x0 * x0; }
            if (full || (row0 + wv * 32 + 16 + qd * 4 + v) < U_NODES) { ss += x1; qq += x1 * x1; }
        }
        s[ct] = ss; sq[ct] = qq;
    }
    float* redS = (float*)smem;            // [16][128]
    float* redQ = (float*)(smem + 8192);   // [16][128]
    int rq = wv * 4 + qd;
    #pragma unroll
    for (int ct = 0; ct < 8; ++ct) {
        redS[rq * 128 + ct * 16 + m] = s[ct];
        redQ[rq * 128 + ct * 16 + m] = sq[ct];
    }
    __syncthreads();
    {
        float tot = 0.f;
        if (t < 128) {
            #pragma unroll
            for (int i = 0; i < 16; ++i) tot += redS[i * 128 + t];
        } else {
            #pragma unroll
            for (int i = 0; i < 16; ++i) tot += redQ[i * 128 + (t - 128)];
        }
        partial[(size_t)blockIdx.x * 256 + t] = tot;
    }
    __syncthreads();

    // ---- h store: AGPR-layout -> LDS transpose -> coalesced bf16x8 stores ----
    unsigned short* tb = (unsigned short*)(smem + wv * 8192);   // [32][128]/wave, 4x8KB=32KB
    #pragma unroll
    for (int ct = 0; ct < 8; ++ct)
        #pragma unroll
        for (int v = 0; v < 4; ++v) {
            tb[(qd * 4 + v) * 128 + ct * 16 + m]        = f2bf(acc0[ct][v]);
            tb[(16 + qd * 4 + v) * 128 + ct * 16 + m]   = f2bf(acc1[ct][v]);
        }
    __syncthreads();
    #pragma unroll
    for (int i = 0; i < 8; ++i) {
        int idx = lane + 64 * i;            // 0..511
        int r = idx >> 4, c8 = (idx & 15) * 8;
        int gr = row0 + wv * 32 + r;
        if (gr < U_NODES)
            *(ushortx8*)(h + (size_t)gr * E_DIM + c8) = *(const ushortx8*)(tb + r * 128 + c8);
    }
}

// ---------------------------------------------------------------------------
// Fold the per-block partials AND finalize BN scale/shift (merged kernels).
// ---------------------------------------------------------------------------
__global__ __launch_bounds__(256) void reduce_finalize_kernel(
    const float* __restrict__ partial,
    const float* __restrict__ gamma, const float* __restrict__ beta,
    float* __restrict__ scale, float* __restrict__ shift)
{
    __shared__ float redS[256], redQ[256];
    const int c = blockIdx.x;       // 0..127
    const int t = threadIdx.x;
    float a = 0.f, b = 0.f;
    for (int j = t; j < NBLK; j += 256) {
        a += partial[(size_t)j * 256 + c];
        b += partial[(size_t)j * 256 + c + 128];
    }
    redS[t] = a; redQ[t] = b;
    __syncthreads();
    #pragma unroll
    for (int s = 128; s > 0; s >>= 1) {
        if (t < s) { redS[t] += redS[t + s]; redQ[t] += redQ[t + s]; }
        __syncthreads();
    }
    if (t == 0) {
        float mu  = redS[0] * (1.f / U_NODES);
        float var = redQ[0] * (1.f / U_NODES) - mu * mu;
        float inv = rsqrtf(var + 1e-5f);
        float sc  = gamma[c] * inv;
        scale[c] = sc;
        shift[c] = beta[c] - sc * mu;
    }
}

// ---------------------------------------------------------------------------
// Gather + BN + tanh + mean over K=33 (R2-VERIFIED version).
// ---------------------------------------------------------------------------
__global__ __launch_bounds__(256) void gather_kernel(
    const unsigned short* __restrict__ h, const int* __restrict__ sidx_g,
    const float* __restrict__ scale, const float* __restrict__ shift,
    float* __restrict__ out)
{
    __shared__ int sl[16 * K_S];
    const int t  = threadIdx.x;
    const int g  = t & 15;          // col group: cols g*8..g*8+7
    const int r  = t >> 4;          // row within block
    const int b0 = blockIdx.x * 16;
    for (int i = t; i < 16 * K_S; i += 256) sl[i] = sidx_g[(size_t)b0 * K_S + i];
    float scv[8], shv[8];
    *(float4*)&scv[0] = *(const float4*)(scale + g * 8);
    *(float4*)&scv[4] = *(const float4*)(scale + g * 8 + 4);
    *(float4*)&shv[0] = *(const float4*)(shift + g * 8);
    *(float4*)&shv[4] = *(const float4*)(shift + g * 8 + 4);
    __syncthreads();

    float acc[8] = {0.f, 0.f, 0.f, 0.f, 0.f, 0.f, 0.f, 0.f};
    #pragma unroll
    for (int k = 0; k < K_S; ++k) {
        int idx = sl[r * K_S + k];
        ushortx8 v = *(const ushortx8*)(h + (size_t)idx * E_DIM + g * 8);
        #pragma unroll
        for (int j = 0; j < 8; ++j) {
            float x  = bf2f(v[j]) * scv[j] + shv[j];
            float ex = __expf(2.f * x);                       // tanh = 1 - 2/(e^2x+1)
            acc[j] += 1.f - 2.f * __builtin_amdgcn_rcpf(ex + 1.f);
        }
    }
    float* op = out + (size_t)(b0 + r) * E_DIM + g * 8;
    *(float4*)(op)     = make_float4(acc[0] * (1.f / K_S), acc[1] * (1.f / K_S),
                                     acc[2] * (1.f / K_S), acc[3] * (1.f / K_S));
    *(float4*)(op + 4) = make_float4(acc[4] * (1.f / K_S), acc[5] * (1.f / K_S),
                                     acc[6] * (1.f / K_S), acc[7] * (1.f / K_S));
}

// ---------------------------------------------------------------------------
extern "C" void kernel_launch(void* const* d_in, const int* in_sizes, int n_in,
                              void* d_out, int out_size, void* d_ws, size_t ws_size,
                              hipStream_t stream) {
    const float* features = (const float*)d_in[0];
    const float* W        = (const float*)d_in[1];
    // d_in[2] = bias — provably cancels inside BatchNorm; unused.
    const float* gamma    = (const float*)d_in[3];
    const float* beta     = (const float*)d_in[4];
    const int*   sample   = (const int*)d_in[5];
    float* out = (float*)d_out;

    // ws layout: scale[128] shift[128] | partial[NBLK*256] | Wt[128*256 bf16]
    //            | h[U*128 bf16]
    float* scale   = (float*)d_ws;
    float* shift   = scale + 128;
    float* partial = shift + 128;
    unsigned short* Wt = (unsigned short*)(partial + (size_t)NBLK * 256);
    unsigned short* h  = Wt + 128 * 256;

    wprep_kernel<<<128, 256, 0, stream>>>(W, Wt);
    gemm_stats_kernel<<<NBLK, 256, 0, stream>>>(features, Wt, h, partial);
    reduce_finalize_kernel<<<128, 256, 0, stream>>>(partial, gamma, beta, scale, shift);
    gather_kernel<<<B_ROWS / 16, 256, 0, stream>>>(h, sample, scale, shift, out);
}